// Round 1
// baseline (5894.537 us; speedup 1.0000x reference)
//
#include <hip/hip_runtime.h>
#include <hip/hip_bf16.h>

// Problem dims (fixed)
#define BB 8
#define TT 512
#define SS 512
#define DD 512
#define HH 8
#define DH 64
// M = B*T = 4096 rows for all row-space GEMMs

// ---------------- generic f32 GEMM: C = epilogue((X @ W^T) + bias) ---------
// X: (M,K) row-major, W: (N,K) row-major, C: (M,N).
// out = (acc + bias[n]) * alpha, optional ReLU.
// tile 64x64, K-tile 16, 256 threads, 4x4 per thread.
template <bool RELU>
__global__ __launch_bounds__(256) void gemm_xwt(const float* __restrict__ X,
                                                const float* __restrict__ W,
                                                const float* __restrict__ bias,
                                                float* __restrict__ C,
                                                int M, int N, int K, float alpha) {
    __shared__ float Xs[16][64];
    __shared__ float Ws[16][64];
    const int tid = threadIdx.x;
    const int tx = tid & 15, ty = tid >> 4;
    const int m0 = blockIdx.y * 64, n0 = blockIdx.x * 64;
    const int lrow = tid >> 2;          // 0..63
    const int lk = (tid & 3) * 4;       // 0,4,8,12

    float acc[4][4] = {};

    for (int kt = 0; kt < K; kt += 16) {
        float4 xv = *(const float4*)(X + (size_t)(m0 + lrow) * K + kt + lk);
        float4 wv = *(const float4*)(W + (size_t)(n0 + lrow) * K + kt + lk);
        Xs[lk + 0][lrow] = xv.x; Xs[lk + 1][lrow] = xv.y;
        Xs[lk + 2][lrow] = xv.z; Xs[lk + 3][lrow] = xv.w;
        Ws[lk + 0][lrow] = wv.x; Ws[lk + 1][lrow] = wv.y;
        Ws[lk + 2][lrow] = wv.z; Ws[lk + 3][lrow] = wv.w;
        __syncthreads();
#pragma unroll
        for (int kk = 0; kk < 16; ++kk) {
            float4 a = *(const float4*)&Xs[kk][ty * 4];
            float4 b = *(const float4*)&Ws[kk][tx * 4];
            float af[4] = {a.x, a.y, a.z, a.w};
            float bf[4] = {b.x, b.y, b.z, b.w};
#pragma unroll
            for (int i = 0; i < 4; ++i)
#pragma unroll
                for (int j = 0; j < 4; ++j) acc[i][j] += af[i] * bf[j];
        }
        __syncthreads();
    }

#pragma unroll
    for (int i = 0; i < 4; ++i) {
        const int m = m0 + ty * 4 + i;
#pragma unroll
        for (int j = 0; j < 4; ++j) {
            const int n = n0 + tx * 4 + j;
            float v = (acc[i][j] + bias[n]) * alpha;
            if (RELU) v = fmaxf(v, 0.f);
            C[(size_t)m * N + n] = v;
        }
    }
}

// ---------------- self-attention, one (b,h,t) row per block ----------------
// QKV layout: (B*T, 1536), q at col h*64+e, k at 512+h*64+e, v at 1024+h*64+e.
// out: (B*T, 512) at col h*64+e. score = (q.k)*0.125 + mask[t][s].
__global__ __launch_bounds__(256) void attn_self(const float* __restrict__ QKV,
                                                 const float* __restrict__ mask,
                                                 float* __restrict__ out) {
    const int t = blockIdx.x, h = blockIdx.y, b = blockIdx.z;
    const int tid = threadIdx.x;
    __shared__ float q[64];
    __shared__ float sc[512];
    __shared__ float red[256];
    __shared__ float pv[4][64];

    if (tid < 64) q[tid] = QKV[(size_t)(b * TT + t) * 1536 + h * 64 + tid];
    __syncthreads();

    const float4* q4 = (const float4*)q;
    for (int s = tid; s < TT; s += 256) {
        const float4* k4 = (const float4*)(QKV + (size_t)(b * TT + s) * 1536 + 512 + h * 64);
        float dot = 0.f;
#pragma unroll
        for (int e = 0; e < 16; ++e) {
            float4 a = q4[e], c = k4[e];
            dot += a.x * c.x + a.y * c.y + a.z * c.z + a.w * c.w;
        }
        sc[s] = dot * 0.125f + mask[t * TT + s];
    }
    __syncthreads();

    // max
    red[tid] = fmaxf(sc[tid], sc[tid + 256]);
    __syncthreads();
#pragma unroll
    for (int o = 128; o > 0; o >>= 1) {
        if (tid < o) red[tid] = fmaxf(red[tid], red[tid + o]);
        __syncthreads();
    }
    const float rowmax = red[0];
    __syncthreads();

    // exp + sum
    float e0 = expf(sc[tid] - rowmax);
    float e1 = expf(sc[tid + 256] - rowmax);
    sc[tid] = e0; sc[tid + 256] = e1;
    red[tid] = e0 + e1;
    __syncthreads();
#pragma unroll
    for (int o = 128; o > 0; o >>= 1) {
        if (tid < o) red[tid] += red[tid + o];
        __syncthreads();
    }
    const float inv = 1.f / red[0];
    __syncthreads();

    // PV
    const int e = tid & 63, g = tid >> 6;
    float acc = 0.f;
    for (int s = g; s < TT; s += 4)
        acc += sc[s] * QKV[(size_t)(b * TT + s) * 1536 + 1024 + h * 64 + e];
    pv[g][e] = acc;
    __syncthreads();
    if (g == 0)
        out[(size_t)(b * TT + t) * DD + h * 64 + e] =
            (pv[0][e] + pv[1][e] + pv[2][e] + pv[3][e]) * inv;
}

// ---------------- gated cross-attention, one (b,h,t) row per block ---------
// CQ: (B*T,512) pre-scaled queries. CV: (B*S,512) values.
// qW_d = sum_e cq_e * ca_in_w[512 + h*64+e][d];  qwg_d = qW_d * gate[t][d]
// qb   = sum_e cq_e * ca_in_b[512 + h*64+e]
// score_s = sum_d qwg_d * memory[b][s][d] + qb   (no mask)
__global__ __launch_bounds__(256) void attn_cross(const float* __restrict__ CQ,
                                                  const float* __restrict__ CV,
                                                  const float* __restrict__ mem,
                                                  const float* __restrict__ caw,
                                                  const float* __restrict__ cab,
                                                  const float* __restrict__ gate,
                                                  float* __restrict__ out) {
    const int t = blockIdx.x, h = blockIdx.y, b = blockIdx.z;
    const int tid = threadIdx.x;
    __shared__ float cq[64];
    __shared__ float qwg[512];
    __shared__ float sc[512];
    __shared__ float red[256];
    __shared__ float pv[4][64];

    if (tid < 64) cq[tid] = CQ[(size_t)(b * TT + t) * DD + h * 64 + tid];
    __syncthreads();

    for (int d = tid; d < DD; d += 256) {
        float a = 0.f;
        const float* wcol = caw + (size_t)(512 + h * 64) * DD + d;
#pragma unroll 8
        for (int e = 0; e < 64; ++e) a += cq[e] * wcol[(size_t)e * DD];
        qwg[d] = a * gate[t * DD + d];
    }
    float qb = 0.f;
#pragma unroll 8
    for (int e = 0; e < 64; ++e) qb += cq[e] * cab[512 + h * 64 + e];
    __syncthreads();

    const float4* w4 = (const float4*)qwg;
    for (int s = tid; s < SS; s += 256) {
        const float4* m4 = (const float4*)(mem + (size_t)(b * SS + s) * DD);
        float dot = 0.f;
#pragma unroll 16
        for (int d4 = 0; d4 < 128; ++d4) {
            float4 a = w4[d4], c = m4[d4];
            dot += a.x * c.x + a.y * c.y + a.z * c.z + a.w * c.w;
        }
        sc[s] = dot + qb;
    }
    __syncthreads();

    red[tid] = fmaxf(sc[tid], sc[tid + 256]);
    __syncthreads();
#pragma unroll
    for (int o = 128; o > 0; o >>= 1) {
        if (tid < o) red[tid] = fmaxf(red[tid], red[tid + o]);
        __syncthreads();
    }
    const float rowmax = red[0];
    __syncthreads();

    float e0 = expf(sc[tid] - rowmax);
    float e1 = expf(sc[tid + 256] - rowmax);
    sc[tid] = e0; sc[tid + 256] = e1;
    red[tid] = e0 + e1;
    __syncthreads();
#pragma unroll
    for (int o = 128; o > 0; o >>= 1) {
        if (tid < o) red[tid] += red[tid + o];
        __syncthreads();
    }
    const float inv = 1.f / red[0];
    __syncthreads();

    const int e = tid & 63, g = tid >> 6;
    float acc = 0.f;
    for (int s = g; s < SS; s += 4)
        acc += sc[s] * CV[(size_t)(b * SS + s) * DD + h * 64 + e];
    pv[g][e] = acc;
    __syncthreads();
    if (g == 0)
        out[(size_t)(b * TT + t) * DD + h * 64 + e] =
            (pv[0][e] + pv[1][e] + pv[2][e] + pv[3][e]) * inv;
}

// ---------------- fused residual + LayerNorm, one row per block ------------
// out[row] = LN(R1[row] + R2[row]) * g + b   (512 cols, 256 threads, 2/thread)
__global__ __launch_bounds__(256) void add_ln(const float* __restrict__ R1,
                                              const float* __restrict__ R2,
                                              const float* __restrict__ g,
                                              const float* __restrict__ bta,
                                              float* __restrict__ out) {
    const int row = blockIdx.x, tid = threadIdx.x;
    const float2 a = ((const float2*)(R1 + (size_t)row * DD))[tid];
    const float2 c = ((const float2*)(R2 + (size_t)row * DD))[tid];
    const float x0 = a.x + c.x, x1 = a.y + c.y;

    __shared__ float2 red[256];
    red[tid] = make_float2(x0 + x1, x0 * x0 + x1 * x1);
    __syncthreads();
#pragma unroll
    for (int o = 128; o > 0; o >>= 1) {
        if (tid < o) {
            red[tid].x += red[tid + o].x;
            red[tid].y += red[tid + o].y;
        }
        __syncthreads();
    }
    const float mean = red[0].x * (1.f / 512.f);
    const float var = red[0].y * (1.f / 512.f) - mean * mean;
    const float rstd = rsqrtf(var + 1e-5f);
    const int i = tid * 2;
    const float y0 = (x0 - mean) * rstd * g[i] + bta[i];
    const float y1 = (x1 - mean) * rstd * g[i + 1] + bta[i + 1];
    ((float2*)(out + (size_t)row * DD))[tid] = make_float2(y0, y1);
}

extern "C" void kernel_launch(void* const* d_in, const int* in_sizes, int n_in,
                              void* d_out, int out_size, void* d_ws, size_t ws_size,
                              hipStream_t stream) {
    const float* tgt      = (const float*)d_in[0];
    const float* memory   = (const float*)d_in[1];
    const float* tgt_mask = (const float*)d_in[2];
    const float* gate     = (const float*)d_in[3];
    const float* sa_in_w  = (const float*)d_in[4];
    const float* sa_in_b  = (const float*)d_in[5];
    const float* sa_out_w = (const float*)d_in[6];
    const float* sa_out_b = (const float*)d_in[7];
    const float* ca_in_w  = (const float*)d_in[8];
    const float* ca_in_b  = (const float*)d_in[9];
    const float* ca_out_w = (const float*)d_in[10];
    const float* ca_out_b = (const float*)d_in[11];
    const float* ff1_w    = (const float*)d_in[12];
    const float* ff1_b    = (const float*)d_in[13];
    const float* ff2_w    = (const float*)d_in[14];
    const float* ff2_b    = (const float*)d_in[15];
    const float* ln1_g    = (const float*)d_in[16];
    const float* ln1_b    = (const float*)d_in[17];
    const float* ln2_g    = (const float*)d_in[18];
    const float* ln2_b    = (const float*)d_in[19];
    const float* ln3_g    = (const float*)d_in[20];
    const float* ln3_b    = (const float*)d_in[21];

    float* ws  = (float*)d_ws;
    float* A   = ws;                       // 8,388,608 floats (QKV / ca_pre / FFN hidden)
    float* Bf  = ws + 8388608;             // 4,194,304 floats (sa_pre / cq+cv / ff2out)
    float* X1  = ws + 8388608 + 4194304;   // 2,097,152 floats (x after ln1)
    float* out = (float*)d_out;            // also holds x2 (after ln2)

    const int M = BB * TT;  // 4096
    const dim3 blk(256);
    const dim3 attn_grid(TT, HH, BB);

    // 1. self-attn QKV projection: (4096,512) @ (1536,512)^T -> A (4096,1536)
    gemm_xwt<false><<<dim3(1536 / 64, M / 64), blk, 0, stream>>>(
        tgt, sa_in_w, sa_in_b, A, M, 1536, 512, 1.f);
    // 2. self attention -> Bf[0:2.1M] (sa_pre, (4096,512))
    attn_self<<<attn_grid, blk, 0, stream>>>(A, tgt_mask, Bf);
    // 3. out-proj -> A+6291456 ; x1 = LN(tgt + proj) -> X1
    gemm_xwt<false><<<dim3(512 / 64, M / 64), blk, 0, stream>>>(
        Bf, sa_out_w, sa_out_b, A + 6291456, M, 512, 512, 1.f);
    add_ln<<<M, blk, 0, stream>>>(tgt, A + 6291456, ln1_g, ln1_b, X1);

    // 4. cq = (x1 @ Wq^T + bq) * 0.125 -> Bf[0:2.1M] ; cv = mem @ Wv^T + bv -> Bf[2.1M:]
    gemm_xwt<false><<<dim3(512 / 64, M / 64), blk, 0, stream>>>(
        X1, ca_in_w, ca_in_b, Bf, M, 512, 512, 0.125f);
    gemm_xwt<false><<<dim3(512 / 64, M / 64), blk, 0, stream>>>(
        memory, ca_in_w + (size_t)1024 * 512, ca_in_b + 1024, Bf + 2097152,
        BB * SS, 512, 512, 1.f);
    // 5. gated cross attention -> A[0:2.1M] (ca_pre)
    attn_cross<<<attn_grid, blk, 0, stream>>>(Bf, Bf + 2097152, memory,
                                              ca_in_w, ca_in_b, gate, A);
    // 6. out-proj -> A+2097152 ; x2 = LN(x1 + proj) -> d_out
    gemm_xwt<false><<<dim3(512 / 64, M / 64), blk, 0, stream>>>(
        A, ca_out_w, ca_out_b, A + 2097152, M, 512, 512, 1.f);
    add_ln<<<M, blk, 0, stream>>>(X1, A + 2097152, ln2_g, ln2_b, out);

    // 7. FFN hidden = relu(x2 @ ff1^T + b) -> A (4096,2048)
    gemm_xwt<true><<<dim3(2048 / 64, M / 64), blk, 0, stream>>>(
        out, ff1_w, ff1_b, A, M, 2048, 512, 1.f);
    // 8. ff2 -> Bf[0:2.1M] ; out = LN(x2 + ff2out)
    gemm_xwt<false><<<dim3(512 / 64, M / 64), blk, 0, stream>>>(
        A, ff2_w, ff2_b, Bf, M, 512, 2048, 1.f);
    add_ln<<<M, blk, 0, stream>>>(out, Bf, ln3_g, ln3_b, out);

    (void)in_sizes; (void)n_in; (void)out_size; (void)ws_size;
}

// Round 2
// 427.118 us; speedup vs baseline: 13.8007x; 13.8007x over previous
//
#include <hip/hip_runtime.h>
#include <hip/hip_bf16.h>

#define BB 8
#define TT 512
#define SS 512
#define DD 512
#define HH 8

typedef __attribute__((ext_vector_type(8))) short bf16x8;
typedef __attribute__((ext_vector_type(4))) float f32x4;
typedef unsigned short u16;

__device__ inline u16 f2b(float f) {
    __hip_bfloat16 h = __float2bfloat16(f);
    return *reinterpret_cast<u16*>(&h);
}

// ============ bf16 MFMA GEMM: C = epi((X @ op(W)) + bias) ============
// X: (M,K) f32, lda row stride. W: TRANSB? (K,N) : (N,K), ldw row stride.
// 64x64 tile, BK=32, 256 thr (4 waves), wave w -> rows [16w,16w+16) x 64 cols.
// GATE: v *= gate[(m&511)*512 + n] (no bias/alpha). OutT in {float, u16(bf16)}.
template <bool RELU, bool TRANSB, bool GATE, typename OutT>
__global__ __launch_bounds__(256) void gemm_mfma(
    const float* __restrict__ X, int lda,
    const float* __restrict__ W, int ldw,
    const float* __restrict__ bias, const float* __restrict__ gate,
    OutT* __restrict__ C, int ldo,
    int M, int N, int K, float alpha,
    int xz, int wz, int oz) {
    __shared__ __align__(16) u16 As[64][40];
    __shared__ __align__(16) u16 Bs[64][40];
    const int tid = threadIdx.x;
    const int wave = tid >> 6, lane = tid & 63;
    const int lm = lane & 15, lg = lane >> 4;
    const int m0 = blockIdx.y * 64, n0 = blockIdx.x * 64;

    X += (size_t)blockIdx.z * xz;
    W += (size_t)blockIdx.z * wz;
    C += (size_t)blockIdx.z * oz;

    f32x4 acc[4];
#pragma unroll
    for (int nt = 0; nt < 4; ++nt) acc[nt] = (f32x4){0.f, 0.f, 0.f, 0.f};

    for (int kt = 0; kt < K; kt += 32) {
        // stage A (64 rows x 32 k)
#pragma unroll
        for (int i = 0; i < 2; ++i) {
            const int idx = tid * 2 + i;
            const int r = idx >> 3, c = (idx & 7) * 4;
            float4 v = *(const float4*)(X + (size_t)(m0 + r) * lda + kt + c);
            As[r][c + 0] = f2b(v.x); As[r][c + 1] = f2b(v.y);
            As[r][c + 2] = f2b(v.z); As[r][c + 3] = f2b(v.w);
        }
        if constexpr (!TRANSB) {
#pragma unroll
            for (int i = 0; i < 2; ++i) {
                const int idx = tid * 2 + i;
                const int r = idx >> 3, c = (idx & 7) * 4;
                float4 v = *(const float4*)(W + (size_t)(n0 + r) * ldw + kt + c);
                Bs[r][c + 0] = f2b(v.x); Bs[r][c + 1] = f2b(v.y);
                Bs[r][c + 2] = f2b(v.z); Bs[r][c + 3] = f2b(v.w);
            }
        } else {
#pragma unroll
            for (int i = 0; i < 2; ++i) {
                const int idx = tid * 2 + i;
                const int kr = idx >> 4, nc = (idx & 15) * 4;
                float4 v = *(const float4*)(W + (size_t)(kt + kr) * ldw + n0 + nc);
                Bs[nc + 0][kr] = f2b(v.x); Bs[nc + 1][kr] = f2b(v.y);
                Bs[nc + 2][kr] = f2b(v.z); Bs[nc + 3][kr] = f2b(v.w);
            }
        }
        __syncthreads();
        const bf16x8 af = *(const bf16x8*)&As[wave * 16 + lm][lg * 8];
#pragma unroll
        for (int nt = 0; nt < 4; ++nt) {
            const bf16x8 bf = *(const bf16x8*)&Bs[nt * 16 + lm][lg * 8];
            acc[nt] = __builtin_amdgcn_mfma_f32_16x16x32_bf16(af, bf, acc[nt], 0, 0, 0);
        }
        __syncthreads();
    }

#pragma unroll
    for (int nt = 0; nt < 4; ++nt) {
#pragma unroll
        for (int r = 0; r < 4; ++r) {
            const int m = m0 + wave * 16 + lg * 4 + r;
            const int n = n0 + nt * 16 + lm;
            float v = acc[nt][r];
            if constexpr (GATE) {
                v *= gate[(size_t)(m & 511) * 512 + n];
            } else {
                v = (v + bias[n]) * alpha;
            }
            if constexpr (RELU) v = fmaxf(v, 0.f);
            if constexpr (sizeof(OutT) == 2) C[(size_t)m * ldo + n] = (OutT)f2b(v);
            else                             C[(size_t)m * ldo + n] = v;
        }
    }
}

// ============ 1-wave flash attention (16 q-rows per block) ============
// Q: bf16 rows (b*TT+t), K/V: bf16 rows (b*SS+s). Per-head col offsets qcs/kcs/vcs.
// scores = (Q.K)*scale [+ mask[t][s]], online softmax over s in chunks of 32,
// PV via MFMA into 16x64 f32 acc. out: f32 (B*T,512) col h*64.
template <int DK, bool HASMASK>
__global__ __launch_bounds__(64) void flash_attn(
    const u16* __restrict__ Qb, int ldq, int qcs,
    const u16* __restrict__ Kb, int ldk, int kcs,
    const u16* __restrict__ Vb, int ldv, int vcs,
    const float* __restrict__ mask, float scale,
    float* __restrict__ out) {
    const int t0 = blockIdx.x * 16;
    const int h = blockIdx.y;
    const int b = blockIdx.z;
    const int lane = threadIdx.x;
    const int lm = lane & 15, lg = lane >> 4;

    __shared__ __align__(16) u16 P[16][40];
    __shared__ __align__(16) u16 Vt[64][40];

    const u16* Q = Qb + (size_t)(b * TT + t0) * ldq + h * qcs;
    const u16* Kp = Kb + (size_t)b * SS * ldk + h * kcs;
    const u16* Vp = Vb + (size_t)b * SS * ldv + h * vcs;

    constexpr int NF = DK / 32;
    bf16x8 qf[NF];
#pragma unroll
    for (int f = 0; f < NF; ++f)
        qf[f] = *(const bf16x8*)(Q + (size_t)lm * ldq + f * 32 + lg * 8);

    float m_run[4], l_run[4];
    f32x4 oacc[4];
#pragma unroll
    for (int r = 0; r < 4; ++r) { m_run[r] = -3e38f; l_run[r] = 0.f; }
#pragma unroll
    for (int nt = 0; nt < 4; ++nt) oacc[nt] = (f32x4){0.f, 0.f, 0.f, 0.f};

    const int smax = HASMASK ? (t0 + 16 < SS ? t0 + 16 : SS) : SS;
    for (int s0 = 0; s0 < smax; s0 += 32) {
        // ---- QK^T for 16t x 32s ----
        f32x4 sc0 = (f32x4){0.f, 0.f, 0.f, 0.f};
        f32x4 sc1 = (f32x4){0.f, 0.f, 0.f, 0.f};
#pragma unroll 4
        for (int f = 0; f < NF; ++f) {
            const bf16x8 k0 = *(const bf16x8*)(Kp + (size_t)(s0 + lm) * ldk + f * 32 + lg * 8);
            const bf16x8 k1 = *(const bf16x8*)(Kp + (size_t)(s0 + 16 + lm) * ldk + f * 32 + lg * 8);
            sc0 = __builtin_amdgcn_mfma_f32_16x16x32_bf16(qf[f], k0, sc0, 0, 0, 0);
            sc1 = __builtin_amdgcn_mfma_f32_16x16x32_bf16(qf[f], k1, sc1, 0, 0, 0);
        }
        float sv0[4], sv1[4];
#pragma unroll
        for (int r = 0; r < 4; ++r) {
            sv0[r] = sc0[r] * scale;
            sv1[r] = sc1[r] * scale;
            if constexpr (HASMASK) {
                const int t = t0 + lg * 4 + r;
                sv0[r] += mask[(size_t)t * SS + s0 + lm];
                sv1[r] += mask[(size_t)t * SS + s0 + 16 + lm];
            }
        }
        // ---- row max across the 16-lane group ----
        float tm[4];
#pragma unroll
        for (int r = 0; r < 4; ++r) tm[r] = fmaxf(sv0[r], sv1[r]);
#pragma unroll
        for (int off = 1; off < 16; off <<= 1)
#pragma unroll
            for (int r = 0; r < 4; ++r) tm[r] = fmaxf(tm[r], __shfl_xor(tm[r], off));
        // ---- online softmax update + P tile ----
        float fac[4], rs[4];
#pragma unroll
        for (int r = 0; r < 4; ++r) {
            const float mn = fmaxf(m_run[r], tm[r]);
            fac[r] = __expf(m_run[r] - mn);
            m_run[r] = mn;
            const float p0 = __expf(sv0[r] - mn);
            const float p1 = __expf(sv1[r] - mn);
            P[lg * 4 + r][lm] = f2b(p0);
            P[lg * 4 + r][16 + lm] = f2b(p1);
            rs[r] = p0 + p1;
        }
#pragma unroll
        for (int off = 1; off < 16; off <<= 1)
#pragma unroll
            for (int r = 0; r < 4; ++r) rs[r] += __shfl_xor(rs[r], off);
#pragma unroll
        for (int r = 0; r < 4; ++r) l_run[r] = l_run[r] * fac[r] + rs[r];
#pragma unroll
        for (int nt = 0; nt < 4; ++nt)
#pragma unroll
            for (int r = 0; r < 4; ++r) oacc[nt][r] *= fac[r];
        // ---- stage V^T (32s x 64dh -> Vt[dh][s]) ----
        {
            const int sl = lane & 31, dh0 = (lane >> 5) * 32;
#pragma unroll
            for (int c = 0; c < 4; ++c) {
                const bf16x8 vv = *(const bf16x8*)(Vp + (size_t)(s0 + sl) * ldv + dh0 + c * 8);
#pragma unroll
                for (int j = 0; j < 8; ++j) Vt[dh0 + c * 8 + j][sl] = (u16)vv[j];
            }
        }
        // ---- PV: out += P(16x32) @ V(32x64) ----
        const bf16x8 pf = *(const bf16x8*)&P[lm][lg * 8];
#pragma unroll
        for (int nt = 0; nt < 4; ++nt) {
            const bf16x8 vf = *(const bf16x8*)&Vt[nt * 16 + lm][lg * 8];
            oacc[nt] = __builtin_amdgcn_mfma_f32_16x16x32_bf16(pf, vf, oacc[nt], 0, 0, 0);
        }
    }
    // ---- write ----
#pragma unroll
    for (int nt = 0; nt < 4; ++nt)
#pragma unroll
        for (int r = 0; r < 4; ++r) {
            const int t = t0 + lg * 4 + r;
            out[(size_t)(b * TT + t) * DD + h * 64 + nt * 16 + lm] = oacc[nt][r] / l_run[r];
        }
}

// ============ f32 -> bf16 cast ============
__global__ __launch_bounds__(256) void cast_bf16(const float* __restrict__ in,
                                                 u16* __restrict__ out, int n4) {
    const int i = blockIdx.x * 256 + threadIdx.x;
    if (i < n4) {
        float4 v = ((const float4*)in)[i];
        ushort4 u;
        u.x = f2b(v.x); u.y = f2b(v.y); u.z = f2b(v.z); u.w = f2b(v.w);
        ((ushort4*)out)[i] = u;
    }
}

// ============ fused residual + LayerNorm ============
__global__ __launch_bounds__(256) void add_ln(const float* __restrict__ R1,
                                              const float* __restrict__ R2,
                                              const float* __restrict__ g,
                                              const float* __restrict__ bta,
                                              float* __restrict__ out) {
    const int row = blockIdx.x, tid = threadIdx.x;
    const float2 a = ((const float2*)(R1 + (size_t)row * DD))[tid];
    const float2 c = ((const float2*)(R2 + (size_t)row * DD))[tid];
    const float x0 = a.x + c.x, x1 = a.y + c.y;

    __shared__ float2 red[256];
    red[tid] = make_float2(x0 + x1, x0 * x0 + x1 * x1);
    __syncthreads();
#pragma unroll
    for (int o = 128; o > 0; o >>= 1) {
        if (tid < o) {
            red[tid].x += red[tid + o].x;
            red[tid].y += red[tid + o].y;
        }
        __syncthreads();
    }
    const float mean = red[0].x * (1.f / 512.f);
    const float var = red[0].y * (1.f / 512.f) - mean * mean;
    const float rstd = rsqrtf(var + 1e-5f);
    const int i = tid * 2;
    const float y0 = (x0 - mean) * rstd * g[i] + bta[i];
    const float y1 = (x1 - mean) * rstd * g[i + 1] + bta[i + 1];
    ((float2*)(out + (size_t)row * DD))[tid] = make_float2(y0, y1);
}

extern "C" void kernel_launch(void* const* d_in, const int* in_sizes, int n_in,
                              void* d_out, int out_size, void* d_ws, size_t ws_size,
                              hipStream_t stream) {
    const float* tgt      = (const float*)d_in[0];
    const float* memory   = (const float*)d_in[1];
    const float* tgt_mask = (const float*)d_in[2];
    const float* gate     = (const float*)d_in[3];
    const float* sa_in_w  = (const float*)d_in[4];
    const float* sa_in_b  = (const float*)d_in[5];
    const float* sa_out_w = (const float*)d_in[6];
    const float* sa_out_b = (const float*)d_in[7];
    const float* ca_in_w  = (const float*)d_in[8];
    const float* ca_in_b  = (const float*)d_in[9];
    const float* ca_out_w = (const float*)d_in[10];
    const float* ca_out_b = (const float*)d_in[11];
    const float* ff1_w    = (const float*)d_in[12];
    const float* ff1_b    = (const float*)d_in[13];
    const float* ff2_w    = (const float*)d_in[14];
    const float* ff2_b    = (const float*)d_in[15];
    const float* ln1_g    = (const float*)d_in[16];
    const float* ln1_b    = (const float*)d_in[17];
    const float* ln2_g    = (const float*)d_in[18];
    const float* ln2_b    = (const float*)d_in[19];
    const float* ln3_g    = (const float*)d_in[20];
    const float* ln3_b    = (const float*)d_in[21];

    float* ws  = (float*)d_ws;
    // Region R (8,388,608 f32 words): QKVb(bf16) / proj / QW(bf16) / FFN hidden
    float* R    = ws;
    float* F1   = ws + 8388608;    // 2,097,152 f32: sa_pre / cq / ca_pre / ff2o
    float* X1p  = ws + 10485760;   // 2,097,152 f32: x1
    u16*   CVb  = (u16*)(ws + 12582912);  // 2,097,152 bf16
    u16*   MBb  = (u16*)(ws + 13631488);  // 2,097,152 bf16
    u16*   QKVb = (u16*)R;          // 4096 x 1536 bf16
    u16*   QW   = (u16*)R;          // 4096 x 4096 bf16 (qWg, col h*512)
    float* HHp  = R;                // 4096 x 2048 f32
    float* PRJ  = R;                // 4096 x 512 f32 (proj1/proj2)
    float* out  = (float*)d_out;

    const int M = BB * TT;  // 4096
    const dim3 blk(256);
    const dim3 fgrid(TT / 16, HH, BB);

    // 1. QKV = tgt @ sa_in_w^T + b  -> bf16 (4096,1536)
    gemm_mfma<false, false, false, u16><<<dim3(1536 / 64, M / 64, 1), blk, 0, stream>>>(
        tgt, 512, sa_in_w, 512, sa_in_b, nullptr, QKVb, 1536, M, 1536, 512, 1.f, 0, 0, 0);
    // 2. self flash attention -> F1 (sa_pre)
    flash_attn<64, true><<<fgrid, dim3(64), 0, stream>>>(
        QKVb, 1536, 64, QKVb + 512, 1536, 64, QKVb + 1024, 1536, 64,
        tgt_mask, 0.125f, F1);
    // 3. proj1 + LN1
    gemm_mfma<false, false, false, float><<<dim3(512 / 64, M / 64, 1), blk, 0, stream>>>(
        F1, 512, sa_out_w, 512, sa_out_b, nullptr, PRJ, 512, M, 512, 512, 1.f, 0, 0, 0);
    add_ln<<<M, blk, 0, stream>>>(tgt, PRJ, ln1_g, ln1_b, X1p);
    // 4. cq = (x1 @ Wq^T + bq) * 0.125 -> F1 (f32)
    gemm_mfma<false, false, false, float><<<dim3(512 / 64, M / 64, 1), blk, 0, stream>>>(
        X1p, 512, ca_in_w, 512, ca_in_b, nullptr, F1, 512, M, 512, 512, 0.125f, 0, 0, 0);
    // 5. cv = mem @ Wv^T + bv -> bf16 CVb
    gemm_mfma<false, false, false, u16><<<dim3(512 / 64, M / 64, 1), blk, 0, stream>>>(
        memory, 512, ca_in_w + (size_t)1024 * 512, 512, ca_in_b + 1024, nullptr,
        CVb, 512, M, 512, 512, 1.f, 0, 0, 0);
    // 6. memory -> bf16
    cast_bf16<<<dim3(2048), blk, 0, stream>>>(memory, MBb, 524288);
    // 7. qWg per head: (cq_h (4096,64)) @ (Wk_h (64,512)) * gate -> QW bf16, col h*512
    gemm_mfma<false, true, true, u16><<<dim3(512 / 64, M / 64, HH), blk, 0, stream>>>(
        F1, 512, ca_in_w + (size_t)512 * 512, 512, nullptr, gate,
        QW, 4096, M, 512, 64, 1.f, 64, 64 * 512, 512);
    // 8. cross flash attention (qb cancels in softmax) -> F1 (ca_pre)
    flash_attn<512, false><<<fgrid, dim3(64), 0, stream>>>(
        QW, 4096, 512, MBb, 512, 0, CVb, 512, 64,
        nullptr, 1.f, F1);
    // 9. proj2 + LN2 -> d_out (x2)
    gemm_mfma<false, false, false, float><<<dim3(512 / 64, M / 64, 1), blk, 0, stream>>>(
        F1, 512, ca_out_w, 512, ca_out_b, nullptr, PRJ, 512, M, 512, 512, 1.f, 0, 0, 0);
    add_ln<<<M, blk, 0, stream>>>(X1p, PRJ, ln2_g, ln2_b, out);
    // 10. FFN hidden = relu(x2 @ ff1^T + b) -> HHp (4096,2048)
    gemm_mfma<true, false, false, float><<<dim3(2048 / 64, M / 64, 1), blk, 0, stream>>>(
        out, 512, ff1_w, 512, ff1_b, nullptr, HHp, 2048, M, 2048, 512, 1.f, 0, 0, 0);
    // 11. ff2 + LN3 -> d_out
    gemm_mfma<false, false, false, float><<<dim3(512 / 64, M / 64, 1), blk, 0, stream>>>(
        HHp, 2048, ff2_w, 2048, ff2_b, nullptr, F1, 512, M, 512, 2048, 1.f, 0, 0, 0);
    add_ln<<<M, blk, 0, stream>>>(out, F1, ln3_g, ln3_b, out);

    (void)in_sizes; (void)n_in; (void)out_size; (void)ws_size;
}

// Round 3
// 262.821 us; speedup vs baseline: 22.4280x; 1.6251x over previous
//
#include <hip/hip_runtime.h>
#include <hip/hip_bf16.h>

#define BB 8
#define TT 512
#define SS 512
#define DD 512
#define HH 8

typedef __attribute__((ext_vector_type(8))) short bf16x8;
typedef __attribute__((ext_vector_type(4))) float f32x4;
typedef unsigned short u16;

__device__ __forceinline__ u16 f2b(float f) {
    __hip_bfloat16 h = __float2bfloat16(f);
    return *reinterpret_cast<u16*>(&h);
}
__device__ __forceinline__ float b2f(u16 v) {
    unsigned int u = ((unsigned int)v) << 16;
    return __builtin_bit_cast(float, u);
}
// async global->LDS, 16B per lane; lds base must be wave-uniform
__device__ __forceinline__ void g2lds16(const void* g, void* l) {
    __builtin_amdgcn_global_load_lds(
        (const __attribute__((address_space(1))) void*)g,
        (__attribute__((address_space(3))) void*)l, 16, 0, 0);
}

// ================= multi-segment f32 -> bf16 cast =================
struct CastSegs {
    const float* s[9];
    u16* d[9];
    int cum[10];  // prefix sums in float4 units
};
__global__ __launch_bounds__(256) void cast_multi(CastSegs sg) {
    const int total = sg.cum[9];
    for (int i = blockIdx.x * 256 + threadIdx.x; i < total; i += gridDim.x * 256) {
        int k = 0;
#pragma unroll
        for (int j = 1; j < 9; ++j) k += (i >= sg.cum[j]);
        const int loc = i - sg.cum[k];
        float4 v = ((const float4*)sg.s[k])[loc];
        ushort4 u;
        u.x = f2b(v.x); u.y = f2b(v.y); u.z = f2b(v.z); u.w = f2b(v.w);
        ((ushort4*)sg.d[k])[loc] = u;
    }
}

// WkT[h][d][e] = ca_in_w[(512 + h*64 + e)*512 + d]  (bf16 out)
__global__ __launch_bounds__(256) void wkt_kernel(const float* __restrict__ w,
                                                  u16* __restrict__ o) {
    const int idx = blockIdx.x * 256 + threadIdx.x;  // 262144 total
    const int h = idx >> 15, d = (idx >> 6) & 511, e = idx & 63;
    o[idx] = f2b(w[(size_t)(512 + h * 64 + e) * 512 + d]);
}

// ================= bf16 MFMA GEMM, m97-style =================
// C = epi(A(M,K) @ B(N,K)^T). 128 x TN tile, BK=64, 256 thr (2x2 waves).
// A,B bf16 via global_load_lds with pre-swizzled source (XOR (row&7)<<4).
template <int TN, bool RELU, bool GATE>
__global__ __launch_bounds__(256) void gemm_bf16(
    const u16* __restrict__ A, int lda, long az,
    const u16* __restrict__ Bw, int ldb, long bz,
    const float* __restrict__ bias, const float* __restrict__ gate,
    u16* __restrict__ C, int ldo, long cz,
    int K, float alpha) {
    __shared__ __align__(16) u16 As[128 * 64];
    __shared__ __align__(16) u16 Bs[TN * 64];
    const int tid = threadIdx.x;
    const int wave = tid >> 6, lane = tid & 63;
    const int lm = lane & 15, lg = lane >> 4;
    const int wm = wave >> 1, wn = wave & 1;
    const int m0 = blockIdx.y * 128, n0 = blockIdx.x * TN;
    A += (size_t)blockIdx.z * az;
    Bw += (size_t)blockIdx.z * bz;
    C += (size_t)blockIdx.z * cz;

    constexpr int FN = TN / 32;  // n-frags per wave
    f32x4 acc[4][FN];
#pragma unroll
    for (int mi = 0; mi < 4; ++mi)
#pragma unroll
        for (int ni = 0; ni < FN; ++ni) acc[mi][ni] = (f32x4){0.f, 0.f, 0.f, 0.f};

    const int srow = lane >> 3;                              // 0..7
    const int sbyte = ((lane & 7) << 4) ^ (srow << 4);       // swizzled byte in 128B row
    const int xk = (lm & 7) << 4;                            // read-side XOR key

    for (int kt = 0; kt < K; kt += 64) {
        if (kt) __syncthreads();
#pragma unroll
        for (int j = 0; j < 4; ++j) {  // A: 16KB, 4 calls/wave
            const int r = wave * 32 + j * 8;
            g2lds16((const char*)(A + (size_t)(m0 + r + srow) * lda + kt) + sbyte,
                    (char*)As + (size_t)r * 128);
        }
#pragma unroll
        for (int j = 0; j < TN / 32; ++j) {  // B: TN/32 calls/wave
            const int r = wave * (TN / 4) + j * 8;
            g2lds16((const char*)(Bw + (size_t)(n0 + r + srow) * ldb + kt) + sbyte,
                    (char*)Bs + (size_t)r * 128);
        }
        __syncthreads();
#pragma unroll
        for (int kh = 0; kh < 2; ++kh) {
            const int cb = kh * 64 + lg * 16;
            bf16x8 af[4], bfr[FN];
#pragma unroll
            for (int mi = 0; mi < 4; ++mi) {
                const int row = wm * 64 + mi * 16 + lm;
                af[mi] = *(const bf16x8*)((const char*)As + row * 128 + (cb ^ xk));
            }
#pragma unroll
            for (int ni = 0; ni < FN; ++ni) {
                const int row = wn * (TN / 2) + ni * 16 + lm;
                bfr[ni] = *(const bf16x8*)((const char*)Bs + row * 128 + (cb ^ xk));
            }
#pragma unroll
            for (int mi = 0; mi < 4; ++mi)
#pragma unroll
                for (int ni = 0; ni < FN; ++ni)
                    acc[mi][ni] = __builtin_amdgcn_mfma_f32_16x16x32_bf16(
                        af[mi], bfr[ni], acc[mi][ni], 0, 0, 0);
        }
    }
#pragma unroll
    for (int mi = 0; mi < 4; ++mi)
#pragma unroll
        for (int ni = 0; ni < FN; ++ni)
#pragma unroll
            for (int r = 0; r < 4; ++r) {
                const int m = m0 + wm * 64 + mi * 16 + lg * 4 + r;
                const int n = n0 + wn * (TN / 2) + ni * 16 + lm;
                float v = acc[mi][ni][r];
                if constexpr (GATE) v *= gate[(size_t)(m & 511) * 512 + n];
                else                v = (v + bias[n]) * alpha;
                if constexpr (RELU) v = fmaxf(v, 0.f);
                C[(size_t)m * ldo + n] = f2b(v);
            }
}

// ================= self flash attention =================
// 4 waves x 16 q-rows (block = 64 t x 1 h x 1 b). Causal inline. bf16 out.
__global__ __launch_bounds__(256) void flash_self(const u16* __restrict__ QKV,
                                                  u16* __restrict__ out) {
    const int t0 = blockIdx.x * 64, h = blockIdx.y, b = blockIdx.z;
    const int tid = threadIdx.x, wave = tid >> 6, lane = tid & 63;
    const int lm = lane & 15, lg = lane >> 4;
    __shared__ __align__(16) u16 Ks[32 * 64];
    __shared__ __align__(16) u16 Vt[64][40];
    __shared__ __align__(16) u16 P[4][16][40];

    const int tw = t0 + wave * 16;
    const size_t qrow = (size_t)(b * TT + tw + lm) * 1536 + h * 64;
    bf16x8 qf[2];
    qf[0] = *(const bf16x8*)(QKV + qrow + lg * 8);
    qf[1] = *(const bf16x8*)(QKV + qrow + 32 + lg * 8);

    float m_run[4], l_run[4];
    f32x4 oacc[4];
#pragma unroll
    for (int r = 0; r < 4; ++r) { m_run[r] = -3e38f; l_run[r] = 0.f; }
#pragma unroll
    for (int nt = 0; nt < 4; ++nt) oacc[nt] = (f32x4){0.f, 0.f, 0.f, 0.f};

    const int srow = lane >> 3, sbyte = ((lane & 7) << 4) ^ (srow << 4);
    const int xk = (lm & 7) << 4;
    const int smax = t0 + 64;
    for (int s0 = 0; s0 < smax; s0 += 32) {
        if (s0) __syncthreads();
        // K chunk 32x64 bf16 = 4KB; one 1KB call per wave, rows s0+wave*8+srow
        g2lds16((const char*)(QKV + (size_t)(b * TT + s0 + wave * 8 + srow) * 1536 +
                              512 + h * 64) + sbyte,
                (char*)Ks + wave * 1024);
        {   // V transpose-stage
            const int s = tid & 31, d0 = (tid >> 5) * 8;
            bf16x8 vv = *(const bf16x8*)(QKV + (size_t)(b * TT + s0 + s) * 1536 +
                                         1024 + h * 64 + d0);
#pragma unroll
            for (int j = 0; j < 8; ++j) Vt[d0 + j][s] = (u16)vv[j];
        }
        __syncthreads();
        if (s0 <= tw + 15) {
            f32x4 sc0 = (f32x4){0.f, 0.f, 0.f, 0.f};
            f32x4 sc1 = (f32x4){0.f, 0.f, 0.f, 0.f};
#pragma unroll
            for (int f = 0; f < 2; ++f) {
                const int cb = f * 64 + lg * 16;
                bf16x8 k0 = *(const bf16x8*)((const char*)Ks + lm * 128 + (cb ^ xk));
                bf16x8 k1 = *(const bf16x8*)((const char*)Ks + (16 + lm) * 128 + (cb ^ xk));
                sc0 = __builtin_amdgcn_mfma_f32_16x16x32_bf16(qf[f], k0, sc0, 0, 0, 0);
                sc1 = __builtin_amdgcn_mfma_f32_16x16x32_bf16(qf[f], k1, sc1, 0, 0, 0);
            }
            float sv0[4], sv1[4], tm[4];
#pragma unroll
            for (int r = 0; r < 4; ++r) {
                const int t = tw + lg * 4 + r;
                sv0[r] = sc0[r] * 0.125f + ((s0 + lm) <= t ? 0.f : -1e9f);
                sv1[r] = sc1[r] * 0.125f + ((s0 + 16 + lm) <= t ? 0.f : -1e9f);
                tm[r] = fmaxf(sv0[r], sv1[r]);
            }
#pragma unroll
            for (int off = 1; off < 16; off <<= 1)
#pragma unroll
                for (int r = 0; r < 4; ++r) tm[r] = fmaxf(tm[r], __shfl_xor(tm[r], off));
            float fac[4], rs[4];
#pragma unroll
            for (int r = 0; r < 4; ++r) {
                const float mn = fmaxf(m_run[r], tm[r]);
                fac[r] = __expf(m_run[r] - mn);
                m_run[r] = mn;
                const float p0 = __expf(sv0[r] - mn);
                const float p1 = __expf(sv1[r] - mn);
                P[wave][lg * 4 + r][lm] = f2b(p0);
                P[wave][lg * 4 + r][16 + lm] = f2b(p1);
                rs[r] = p0 + p1;
            }
#pragma unroll
            for (int off = 1; off < 16; off <<= 1)
#pragma unroll
                for (int r = 0; r < 4; ++r) rs[r] += __shfl_xor(rs[r], off);
#pragma unroll
            for (int r = 0; r < 4; ++r) l_run[r] = l_run[r] * fac[r] + rs[r];
#pragma unroll
            for (int nt = 0; nt < 4; ++nt)
#pragma unroll
                for (int r = 0; r < 4; ++r) oacc[nt][r] *= fac[r];
            const bf16x8 pf = *(const bf16x8*)&P[wave][lm][lg * 8];
#pragma unroll
            for (int nt = 0; nt < 4; ++nt) {
                const bf16x8 vf = *(const bf16x8*)&Vt[nt * 16 + lm][lg * 8];
                oacc[nt] = __builtin_amdgcn_mfma_f32_16x16x32_bf16(pf, vf, oacc[nt], 0, 0, 0);
            }
        }
    }
#pragma unroll
    for (int nt = 0; nt < 4; ++nt)
#pragma unroll
        for (int r = 0; r < 4; ++r)
            out[(size_t)(b * TT + tw + lg * 4 + r) * DD + h * 64 + nt * 16 + lm] =
                f2b(oacc[nt][r] / l_run[r]);
}

// ================= cross flash attention (DK=512) =================
// QW: (B*T, 2048) bf16 (4 heads per launch, col hl*512). Kmem: (B*S,512) bf16.
// CV: (B*S,512) bf16 col h*64. K chunk 32x512=32KB staged via gload_lds+swizzle.
__global__ __launch_bounds__(256) void flash_cross(
    const u16* __restrict__ QW, const u16* __restrict__ Kmem,
    const u16* __restrict__ CV, int h0, u16* __restrict__ out) {
    const int t0 = blockIdx.x * 64, hl = blockIdx.y, b = blockIdx.z;
    const int h = h0 + hl;
    const int tid = threadIdx.x, wave = tid >> 6, lane = tid & 63;
    const int lm = lane & 15, lg = lane >> 4;
    __shared__ __align__(16) u16 Ks[32 * 512];
    __shared__ __align__(16) u16 Vt[64][40];
    __shared__ __align__(16) u16 P[4][16][40];

    const int tw = t0 + wave * 16;
    const size_t qrow = (size_t)(b * TT + tw + lm) * 2048 + hl * 512;
    bf16x8 qf[16];
#pragma unroll
    for (int f = 0; f < 16; ++f)
        qf[f] = *(const bf16x8*)(QW + qrow + f * 32 + lg * 8);

    float m_run[4], l_run[4];
    f32x4 oacc[4];
#pragma unroll
    for (int r = 0; r < 4; ++r) { m_run[r] = -3e38f; l_run[r] = 0.f; }
#pragma unroll
    for (int nt = 0; nt < 4; ++nt) oacc[nt] = (f32x4){0.f, 0.f, 0.f, 0.f};

    const int xk = (lm & 7) << 4;
    for (int s0 = 0; s0 < SS; s0 += 32) {
        if (s0) __syncthreads();
#pragma unroll
        for (int j = 0; j < 8; ++j) {  // 32 rows x 1KB, 8 calls/wave
            const int row = wave * 8 + j;
            g2lds16((const char*)(Kmem + ((size_t)b * SS + s0 + row) * 512) +
                        ((lane * 16) ^ (j << 4)),
                    (char*)Ks + row * 1024);
        }
        {   // V transpose-stage
            const int s = tid & 31, d0 = (tid >> 5) * 8;
            bf16x8 vv = *(const bf16x8*)(CV + ((size_t)b * SS + s0 + s) * 512 +
                                         h * 64 + d0);
#pragma unroll
            for (int j = 0; j < 8; ++j) Vt[d0 + j][s] = (u16)vv[j];
        }
        __syncthreads();
        f32x4 sc0 = (f32x4){0.f, 0.f, 0.f, 0.f};
        f32x4 sc1 = (f32x4){0.f, 0.f, 0.f, 0.f};
#pragma unroll
        for (int f = 0; f < 16; ++f) {
            const int cb = f * 64 + lg * 16;
            bf16x8 k0 = *(const bf16x8*)((const char*)Ks + lm * 1024 + (cb ^ xk));
            bf16x8 k1 = *(const bf16x8*)((const char*)Ks + (16 + lm) * 1024 + (cb ^ xk));
            sc0 = __builtin_amdgcn_mfma_f32_16x16x32_bf16(qf[f], k0, sc0, 0, 0, 0);
            sc1 = __builtin_amdgcn_mfma_f32_16x16x32_bf16(qf[f], k1, sc1, 0, 0, 0);
        }
        float sv0[4], sv1[4], tm[4];
#pragma unroll
        for (int r = 0; r < 4; ++r) {
            sv0[r] = sc0[r]; sv1[r] = sc1[r];
            tm[r] = fmaxf(sv0[r], sv1[r]);
        }
#pragma unroll
        for (int off = 1; off < 16; off <<= 1)
#pragma unroll
            for (int r = 0; r < 4; ++r) tm[r] = fmaxf(tm[r], __shfl_xor(tm[r], off));
        float fac[4], rs[4];
#pragma unroll
        for (int r = 0; r < 4; ++r) {
            const float mn = fmaxf(m_run[r], tm[r]);
            fac[r] = __expf(m_run[r] - mn);
            m_run[r] = mn;
            const float p0 = __expf(sv0[r] - mn);
            const float p1 = __expf(sv1[r] - mn);
            P[wave][lg * 4 + r][lm] = f2b(p0);
            P[wave][lg * 4 + r][16 + lm] = f2b(p1);
            rs[r] = p0 + p1;
        }
#pragma unroll
        for (int off = 1; off < 16; off <<= 1)
#pragma unroll
            for (int r = 0; r < 4; ++r) rs[r] += __shfl_xor(rs[r], off);
#pragma unroll
        for (int r = 0; r < 4; ++r) l_run[r] = l_run[r] * fac[r] + rs[r];
#pragma unroll
        for (int nt = 0; nt < 4; ++nt)
#pragma unroll
            for (int r = 0; r < 4; ++r) oacc[nt][r] *= fac[r];
        const bf16x8 pf = *(const bf16x8*)&P[wave][lm][lg * 8];
#pragma unroll
        for (int nt = 0; nt < 4; ++nt) {
            const bf16x8 vf = *(const bf16x8*)&Vt[nt * 16 + lm][lg * 8];
            oacc[nt] = __builtin_amdgcn_mfma_f32_16x16x32_bf16(pf, vf, oacc[nt], 0, 0, 0);
        }
    }
#pragma unroll
    for (int nt = 0; nt < 4; ++nt)
#pragma unroll
        for (int r = 0; r < 4; ++r)
            out[(size_t)(b * TT + tw + lg * 4 + r) * DD + h * 64 + nt * 16 + lm] =
                f2b(oacc[nt][r] / l_run[r]);
}

// ================= fused residual + LayerNorm =================
// R2 is bf16. R1 f32 or bf16 (template). Outputs: f32 (nullable) + bf16 (nullable).
template <bool R1B>
__global__ __launch_bounds__(256) void add_ln(
    const void* __restrict__ R1v, const u16* __restrict__ R2,
    const float* __restrict__ g, const float* __restrict__ bta,
    float* __restrict__ outf, u16* __restrict__ outb) {
    const int row = blockIdx.x, tid = threadIdx.x;
    float x0, x1;
    if constexpr (R1B) {
        ushort2 a = ((const ushort2*)((const u16*)R1v + (size_t)row * DD))[tid];
        x0 = b2f(a.x); x1 = b2f(a.y);
    } else {
        float2 a = ((const float2*)((const float*)R1v + (size_t)row * DD))[tid];
        x0 = a.x; x1 = a.y;
    }
    ushort2 c = ((const ushort2*)(R2 + (size_t)row * DD))[tid];
    x0 += b2f(c.x); x1 += b2f(c.y);

    __shared__ float2 red[256];
    red[tid] = make_float2(x0 + x1, x0 * x0 + x1 * x1);
    __syncthreads();
#pragma unroll
    for (int o = 128; o > 0; o >>= 1) {
        if (tid < o) {
            red[tid].x += red[tid + o].x;
            red[tid].y += red[tid + o].y;
        }
        __syncthreads();
    }
    const float mean = red[0].x * (1.f / 512.f);
    const float var = red[0].y * (1.f / 512.f) - mean * mean;
    const float rstd = rsqrtf(var + 1e-5f);
    const int i = tid * 2;
    const float y0 = (x0 - mean) * rstd * g[i] + bta[i];
    const float y1 = (x1 - mean) * rstd * g[i + 1] + bta[i + 1];
    if (outf) ((float2*)(outf + (size_t)row * DD))[tid] = make_float2(y0, y1);
    if (outb) {
        ushort2 ub; ub.x = f2b(y0); ub.y = f2b(y1);
        ((ushort2*)(outb + (size_t)row * DD))[tid] = ub;
    }
}

extern "C" void kernel_launch(void* const* d_in, const int* in_sizes, int n_in,
                              void* d_out, int out_size, void* d_ws, size_t ws_size,
                              hipStream_t stream) {
    const float* tgt      = (const float*)d_in[0];
    const float* memory   = (const float*)d_in[1];
    const float* gate     = (const float*)d_in[3];
    const float* sa_in_w  = (const float*)d_in[4];
    const float* sa_in_b  = (const float*)d_in[5];
    const float* sa_out_w = (const float*)d_in[6];
    const float* sa_out_b = (const float*)d_in[7];
    const float* ca_in_w  = (const float*)d_in[8];
    const float* ca_in_b  = (const float*)d_in[9];
    const float* ca_out_w = (const float*)d_in[10];
    const float* ca_out_b = (const float*)d_in[11];
    const float* ff1_w    = (const float*)d_in[12];
    const float* ff1_b    = (const float*)d_in[13];
    const float* ff2_w    = (const float*)d_in[14];
    const float* ff2_b    = (const float*)d_in[15];
    const float* ln1_g    = (const float*)d_in[16];
    const float* ln1_b    = (const float*)d_in[17];
    const float* ln2_g    = (const float*)d_in[18];
    const float* ln2_b    = (const float*)d_in[19];
    const float* ln3_g    = (const float*)d_in[20];
    const float* ln3_b    = (const float*)d_in[21];

    // ---- workspace layout (u16 units); high-water = 29,360,128 u16 = 56 MB ----
    u16* ws16     = (u16*)d_ws;
    u16* QKVb     = ws16;                    // [0, 6291456)       steps 1-2
    u16* tgtb     = ws16 + 6291456;          // 2097152            step 0-1
    u16* sa_preb  = ws16 + 6291456;          // reuse (tgtb dead)  steps 2-3
    u16* QWa      = ws16;                    // [0, 8388608)       steps 7-8 (ping-pong)
    u16* ca_preb  = ws16 + 8388608;          // 2097152            steps 8-9
    u16* PRJ2b    = ws16 + 10485760;         // 2097152            step 9-10
    u16* HHb      = ws16;                    // [0, 8388608)       steps 11-12
    u16* F1b      = ws16 + 8388608;          // 2097152            step 12-13
    u16* CVb      = ws16 + 12582912;         // 2097152            steps 6-8
    u16* memb     = ws16 + 16777216;         // 2097152
    u16* Wreg     = ws16 + 18874368;
    u16* sa_in_wb = Wreg;                    // 786432
    u16* sa_out_wb= Wreg + 786432;           // 262144
    u16* ca_wq_b  = Wreg + 1048576;          // 262144
    u16* ca_wv_b  = Wreg + 1310720;          // 262144
    u16* WkT      = Wreg + 1572864;          // 262144 (H,512,64)
    u16* ca_out_wb= Wreg + 1835008;          // 262144
    u16* ff1_wb   = Wreg + 2097152;          // 1048576
    u16* ff2_wb   = Wreg + 3145728;          // 1048576
    u16* X1b      = ws16 + 23068672;         // 2097152            steps 4-10
    u16* X2b      = ws16 + 25165824;         // 2097152            steps 10-13
    u16* CQb      = ws16 + 27262976;         // 2097152            steps 5-7
    u16* PRJb     = CQb;                     // steps 3-4 (disjoint lifetime)
    float* outf   = (float*)d_out;

    const dim3 blk(256);

    // 0. casts
    CastSegs sg;
    sg.s[0]=tgt; sg.s[1]=memory; sg.s[2]=sa_in_w; sg.s[3]=sa_out_w;
    sg.s[4]=ca_in_w; sg.s[5]=ca_in_w + (size_t)1024*512; sg.s[6]=ca_out_w;
    sg.s[7]=ff1_w; sg.s[8]=ff2_w;
    sg.d[0]=tgtb; sg.d[1]=memb; sg.d[2]=sa_in_wb; sg.d[3]=sa_out_wb;
    sg.d[4]=ca_wq_b; sg.d[5]=ca_wv_b; sg.d[6]=ca_out_wb;
    sg.d[7]=ff1_wb; sg.d[8]=ff2_wb;
    {
        const int n4[9] = {524288,524288,196608,65536,65536,65536,65536,262144,262144};
        int c = 0;
        for (int i = 0; i < 9; ++i) { sg.cum[i] = c; c += n4[i]; }
        sg.cum[9] = c;
    }
    cast_multi<<<2048, blk, 0, stream>>>(sg);
    wkt_kernel<<<1024, blk, 0, stream>>>(ca_in_w, WkT);

    // 1. QKV (4096,1536) bf16
    gemm_bf16<128,false,false><<<dim3(12,32,1), blk, 0, stream>>>(
        tgtb,512,0, sa_in_wb,512,0, sa_in_b,nullptr, QKVb,1536,0, 512, 1.f);
    // 2. self flash -> sa_preb
    flash_self<<<dim3(8,8,8), blk, 0, stream>>>(QKVb, sa_preb);
    // 3. proj1 -> PRJb
    gemm_bf16<64,false,false><<<dim3(8,32,1), blk, 0, stream>>>(
        sa_preb,512,0, sa_out_wb,512,0, sa_out_b,nullptr, PRJb,512,0, 512, 1.f);
    // 4. LN1 -> X1b
    add_ln<false><<<4096, blk, 0, stream>>>(tgt, PRJb, ln1_g, ln1_b, nullptr, X1b);
    // 5. cq = (x1 @ Wq^T + bq)*0.125 -> CQb
    gemm_bf16<64,false,false><<<dim3(8,32,1), blk, 0, stream>>>(
        X1b,512,0, ca_wq_b,512,0, ca_in_b,nullptr, CQb,512,0, 512, 0.125f);
    // 6. cv -> CVb
    gemm_bf16<64,false,false><<<dim3(8,32,1), blk, 0, stream>>>(
        memb,512,0, ca_wv_b,512,0, ca_in_b+1024,nullptr, CVb,512,0, 512, 1.f);
    // 7a/8a. qWg heads 0-3 -> QWa ; cross flash heads 0-3
    gemm_bf16<64,false,true><<<dim3(8,32,4), blk, 0, stream>>>(
        CQb,512,64, WkT,64,32768, nullptr,gate, QWa,2048,512, 64, 1.f);
    flash_cross<<<dim3(8,4,8), blk, 0, stream>>>(QWa, memb, CVb, 0, ca_preb);
    // 7b/8b. heads 4-7
    gemm_bf16<64,false,true><<<dim3(8,32,4), blk, 0, stream>>>(
        CQb+256,512,64, WkT+4*32768,64,32768, nullptr,gate, QWa,2048,512, 64, 1.f);
    flash_cross<<<dim3(8,4,8), blk, 0, stream>>>(QWa, memb, CVb, 4, ca_preb);
    // 9. proj2 -> PRJ2b
    gemm_bf16<64,false,false><<<dim3(8,32,1), blk, 0, stream>>>(
        ca_preb,512,0, ca_out_wb,512,0, ca_out_b,nullptr, PRJ2b,512,0, 512, 1.f);
    // 10. LN2 -> X2b
    add_ln<true><<<4096, blk, 0, stream>>>(X1b, PRJ2b, ln2_g, ln2_b, nullptr, X2b);
    // 11. ff1 + relu -> HHb (4096,2048)
    gemm_bf16<128,true,false><<<dim3(16,32,1), blk, 0, stream>>>(
        X2b,512,0, ff1_wb,512,0, ff1_b,nullptr, HHb,2048,0, 512, 1.f);
    // 12. ff2 -> F1b
    gemm_bf16<64,false,false><<<dim3(8,32,1), blk, 0, stream>>>(
        HHb,2048,0, ff2_wb,2048,0, ff2_b,nullptr, F1b,512,0, 2048, 1.f);
    // 13. LN3 -> d_out (f32)
    add_ln<true><<<4096, blk, 0, stream>>>(X2b, F1b, ln3_g, ln3_b, outf, nullptr);

    (void)in_sizes; (void)n_in; (void)out_size; (void)ws_size;
}

// Round 4
// 218.231 us; speedup vs baseline: 27.0106x; 1.2043x over previous
//
#include <hip/hip_runtime.h>
#include <hip/hip_bf16.h>

#define BB 8
#define TT 512
#define SS 512
#define DD 512
#define HH 8

typedef __attribute__((ext_vector_type(8))) short bf16x8;
typedef __attribute__((ext_vector_type(4))) float f32x4;
typedef unsigned short u16;

__device__ __forceinline__ u16 f2b(float f) {
    __hip_bfloat16 h = __float2bfloat16(f);
    return *reinterpret_cast<u16*>(&h);
}
__device__ __forceinline__ float b2f(u16 v) {
    unsigned int u = ((unsigned int)v) << 16;
    return __builtin_bit_cast(float, u);
}
__device__ __forceinline__ void g2lds16(const void* g, void* l) {
    __builtin_amdgcn_global_load_lds(
        (const __attribute__((address_space(1))) void*)g,
        (__attribute__((address_space(3))) void*)l, 16, 0, 0);
}
template <int N> __device__ __forceinline__ void waitvm();
template <> __device__ __forceinline__ void waitvm<0>() { asm volatile("s_waitcnt vmcnt(0)" ::: "memory"); }
template <> __device__ __forceinline__ void waitvm<6>() { asm volatile("s_waitcnt vmcnt(6)" ::: "memory"); }
template <> __device__ __forceinline__ void waitvm<8>() { asm volatile("s_waitcnt vmcnt(8)" ::: "memory"); }
template <> __device__ __forceinline__ void waitvm<9>() { asm volatile("s_waitcnt vmcnt(9)" ::: "memory"); }
__device__ __forceinline__ void barrier_raw() {
    asm volatile("" ::: "memory");
    __builtin_amdgcn_s_barrier();
    asm volatile("" ::: "memory");
}

// ================= multi-segment f32 -> bf16 cast =================
struct CastSegs {
    const float* s[9];
    u16* d[9];
    int cum[10];
};
__global__ __launch_bounds__(256) void cast_multi(CastSegs sg) {
    const int total = sg.cum[9];
    for (int i = blockIdx.x * 256 + threadIdx.x; i < total; i += gridDim.x * 256) {
        int k = 0;
#pragma unroll
        for (int j = 1; j < 9; ++j) k += (i >= sg.cum[j]);
        const int loc = i - sg.cum[k];
        float4 v = ((const float4*)sg.s[k])[loc];
        ushort4 u;
        u.x = f2b(v.x); u.y = f2b(v.y); u.z = f2b(v.z); u.w = f2b(v.w);
        ((ushort4*)sg.d[k])[loc] = u;
    }
}

// WkT[h][d][e] = ca_in_w[(512 + h*64 + e)*512 + d]
__global__ __launch_bounds__(256) void wkt_kernel(const float* __restrict__ w,
                                                  u16* __restrict__ o) {
    const int idx = blockIdx.x * 256 + threadIdx.x;  // 262144 total
    const int h = idx >> 15, d = (idx >> 6) & 511, e = idx & 63;
    o[idx] = f2b(w[(size_t)(512 + h * 64 + e) * 512 + d]);
}

// ================= bf16 MFMA GEMM, dbuf prefetch =================
// C = epi(A(M,K) @ B(N,K)^T). 128 x TN tile, BK=64, 256 thr (2x2 waves).
// Per-z bias/alpha: z==0 -> (bias,alpha), z>0 -> (biasB,alphaB).
template <int TN, bool RELU, bool GATE>
__global__ __launch_bounds__(256) void gemm_bf16(
    const u16* __restrict__ A, int lda, long az,
    const u16* __restrict__ Bw, int ldb, long bz,
    const float* __restrict__ bias, const float* __restrict__ biasB,
    const float* __restrict__ gate,
    u16* __restrict__ C, int ldo, long cz,
    int K, float alpha, float alphaB) {
    __shared__ __align__(16) u16 As[2][128 * 64];
    __shared__ __align__(16) u16 Bs[2][TN * 64];
    const int tid = threadIdx.x;
    const int wave = tid >> 6, lane = tid & 63;
    const int lm = lane & 15, lg = lane >> 4;
    const int wm = wave >> 1, wn = wave & 1;
    const int m0 = blockIdx.y * 128, n0 = blockIdx.x * TN;
    A += (size_t)blockIdx.z * az;
    Bw += (size_t)blockIdx.z * bz;
    C += (size_t)blockIdx.z * cz;
    constexpr int FN = TN / 32;
    constexpr int LPS = 4 + TN / 32;

    f32x4 acc[4][FN];
#pragma unroll
    for (int mi = 0; mi < 4; ++mi)
#pragma unroll
        for (int ni = 0; ni < FN; ++ni) acc[mi][ni] = (f32x4){0.f, 0.f, 0.f, 0.f};

    const int srow = lane >> 3;
    const int sbyte = ((lane & 7) << 4) ^ (srow << 4);
    const int xk = (lm & 7) << 4;

    auto stage = [&](int buf, int kt) {
#pragma unroll
        for (int j = 0; j < 4; ++j) {
            const int r = wave * 32 + j * 8;
            g2lds16((const char*)(A + (size_t)(m0 + r + srow) * lda + kt) + sbyte,
                    (char*)As[buf] + (size_t)r * 128);
        }
#pragma unroll
        for (int j = 0; j < FN; ++j) {
            const int r = wave * (TN / 4) + j * 8;
            g2lds16((const char*)(Bw + (size_t)(n0 + r + srow) * ldb + kt) + sbyte,
                    (char*)Bs[buf] + (size_t)r * 128);
        }
    };

    stage(0, 0);
    const int NK = K >> 6;
    for (int t = 0; t < NK; ++t) {
        const int cur = t & 1;
        if (t + 1 < NK) { stage(cur ^ 1, (t + 1) << 6); waitvm<LPS>(); }
        else            { waitvm<0>(); }
        barrier_raw();
#pragma unroll
        for (int kh = 0; kh < 2; ++kh) {
            const int cb = kh * 64 + lg * 16;
            bf16x8 af[4], bfr[FN];
#pragma unroll
            for (int mi = 0; mi < 4; ++mi) {
                const int row = wm * 64 + mi * 16 + lm;
                af[mi] = *(const bf16x8*)((const char*)As[cur] + row * 128 + (cb ^ xk));
            }
#pragma unroll
            for (int ni = 0; ni < FN; ++ni) {
                const int row = wn * (TN / 2) + ni * 16 + lm;
                bfr[ni] = *(const bf16x8*)((const char*)Bs[cur] + row * 128 + (cb ^ xk));
            }
#pragma unroll
            for (int mi = 0; mi < 4; ++mi)
#pragma unroll
                for (int ni = 0; ni < FN; ++ni)
                    acc[mi][ni] = __builtin_amdgcn_mfma_f32_16x16x32_bf16(
                        af[mi], bfr[ni], acc[mi][ni], 0, 0, 0);
        }
        barrier_raw();
    }

    const float* bp = blockIdx.z ? biasB : bias;
    const float al = blockIdx.z ? alphaB : alpha;
#pragma unroll
    for (int mi = 0; mi < 4; ++mi)
#pragma unroll
        for (int ni = 0; ni < FN; ++ni)
#pragma unroll
            for (int r = 0; r < 4; ++r) {
                const int m = m0 + wm * 64 + mi * 16 + lg * 4 + r;
                const int n = n0 + wn * (TN / 2) + ni * 16 + lm;
                float v = acc[mi][ni][r];
                if constexpr (GATE) v *= gate[(size_t)(m & 511) * 512 + n];
                else                v = (v + bp[n]) * al;
                if constexpr (RELU) v = fmaxf(v, 0.f);
                C[(size_t)m * ldo + n] = f2b(v);
            }
}

// ================= self flash attention (round-3, verified) =================
__global__ __launch_bounds__(256) void flash_self(const u16* __restrict__ QKV,
                                                  u16* __restrict__ out) {
    const int t0 = blockIdx.x * 64, h = blockIdx.y, b = blockIdx.z;
    const int tid = threadIdx.x, wave = tid >> 6, lane = tid & 63;
    const int lm = lane & 15, lg = lane >> 4;
    __shared__ __align__(16) u16 Ks[32 * 64];
    __shared__ __align__(16) u16 Vt[64][40];
    __shared__ __align__(16) u16 P[4][16][40];

    const int tw = t0 + wave * 16;
    const size_t qrow = (size_t)(b * TT + tw + lm) * 1536 + h * 64;
    bf16x8 qf[2];
    qf[0] = *(const bf16x8*)(QKV + qrow + lg * 8);
    qf[1] = *(const bf16x8*)(QKV + qrow + 32 + lg * 8);

    float m_run[4], l_run[4];
    f32x4 oacc[4];
#pragma unroll
    for (int r = 0; r < 4; ++r) { m_run[r] = -3e38f; l_run[r] = 0.f; }
#pragma unroll
    for (int nt = 0; nt < 4; ++nt) oacc[nt] = (f32x4){0.f, 0.f, 0.f, 0.f};

    const int srow = lane >> 3, sbyte = ((lane & 7) << 4) ^ (srow << 4);
    const int xk = (lm & 7) << 4;
    const int smax = t0 + 64;
    for (int s0 = 0; s0 < smax; s0 += 32) {
        if (s0) __syncthreads();
        g2lds16((const char*)(QKV + (size_t)(b * TT + s0 + wave * 8 + srow) * 1536 +
                              512 + h * 64) + sbyte,
                (char*)Ks + wave * 1024);
        {
            const int s = tid & 31, d0 = (tid >> 5) * 8;
            bf16x8 vv = *(const bf16x8*)(QKV + (size_t)(b * TT + s0 + s) * 1536 +
                                         1024 + h * 64 + d0);
#pragma unroll
            for (int j = 0; j < 8; ++j) Vt[d0 + j][s] = (u16)vv[j];
        }
        __syncthreads();
        if (s0 <= tw + 15) {
            f32x4 sc0 = (f32x4){0.f, 0.f, 0.f, 0.f};
            f32x4 sc1 = (f32x4){0.f, 0.f, 0.f, 0.f};
#pragma unroll
            for (int f = 0; f < 2; ++f) {
                const int cb = f * 64 + lg * 16;
                bf16x8 k0 = *(const bf16x8*)((const char*)Ks + lm * 128 + (cb ^ xk));
                bf16x8 k1 = *(const bf16x8*)((const char*)Ks + (16 + lm) * 128 + (cb ^ xk));
                sc0 = __builtin_amdgcn_mfma_f32_16x16x32_bf16(qf[f], k0, sc0, 0, 0, 0);
                sc1 = __builtin_amdgcn_mfma_f32_16x16x32_bf16(qf[f], k1, sc1, 0, 0, 0);
            }
            float sv0[4], sv1[4], tm[4];
#pragma unroll
            for (int r = 0; r < 4; ++r) {
                const int t = tw + lg * 4 + r;
                sv0[r] = sc0[r] * 0.125f + ((s0 + lm) <= t ? 0.f : -1e9f);
                sv1[r] = sc1[r] * 0.125f + ((s0 + 16 + lm) <= t ? 0.f : -1e9f);
                tm[r] = fmaxf(sv0[r], sv1[r]);
            }
#pragma unroll
            for (int off = 1; off < 16; off <<= 1)
#pragma unroll
                for (int r = 0; r < 4; ++r) tm[r] = fmaxf(tm[r], __shfl_xor(tm[r], off));
            float fac[4], rs[4];
#pragma unroll
            for (int r = 0; r < 4; ++r) {
                const float mn = fmaxf(m_run[r], tm[r]);
                fac[r] = __expf(m_run[r] - mn);
                m_run[r] = mn;
                const float p0 = __expf(sv0[r] - mn);
                const float p1 = __expf(sv1[r] - mn);
                P[wave][lg * 4 + r][lm] = f2b(p0);
                P[wave][lg * 4 + r][16 + lm] = f2b(p1);
                rs[r] = p0 + p1;
            }
#pragma unroll
            for (int off = 1; off < 16; off <<= 1)
#pragma unroll
                for (int r = 0; r < 4; ++r) rs[r] += __shfl_xor(rs[r], off);
#pragma unroll
            for (int r = 0; r < 4; ++r) l_run[r] = l_run[r] * fac[r] + rs[r];
#pragma unroll
            for (int nt = 0; nt < 4; ++nt)
#pragma unroll
                for (int r = 0; r < 4; ++r) oacc[nt][r] *= fac[r];
            const bf16x8 pf = *(const bf16x8*)&P[wave][lm][lg * 8];
#pragma unroll
            for (int nt = 0; nt < 4; ++nt) {
                const bf16x8 vf = *(const bf16x8*)&Vt[nt * 16 + lm][lg * 8];
                oacc[nt] = __builtin_amdgcn_mfma_f32_16x16x32_bf16(pf, vf, oacc[nt], 0, 0, 0);
            }
        }
    }
#pragma unroll
    for (int nt = 0; nt < 4; ++nt)
#pragma unroll
        for (int r = 0; r < 4; ++r)
            out[(size_t)(b * TT + tw + lg * 4 + r) * DD + h * 64 + nt * 16 + lm] =
                f2b(oacc[nt][r] / l_run[r]);
}

// ================= cross flash attention, dbuf prefetch =================
// QW: (B*T,4096) bf16, head h at col h*512. Kmem: (B*S,512). CV col h*64.
__global__ __launch_bounds__(256) void flash_cross(
    const u16* __restrict__ QW, const u16* __restrict__ Kmem,
    const u16* __restrict__ CV, u16* __restrict__ out) {
    const int t0 = blockIdx.x * 64, h = blockIdx.y, b = blockIdx.z;
    const int tid = threadIdx.x, wave = tid >> 6, lane = tid & 63;
    const int lm = lane & 15, lg = lane >> 4;
    __shared__ __align__(16) u16 Ks[2][32 * 512];
    __shared__ __align__(16) u16 Vt[2][64][40];
    __shared__ __align__(16) u16 P[4][16][40];

    const int tw = t0 + wave * 16;
    const size_t qrow = (size_t)(b * TT + tw + lm) * 4096 + h * 512;
    bf16x8 qf[16];
#pragma unroll
    for (int f = 0; f < 16; ++f)
        qf[f] = *(const bf16x8*)(QW + qrow + f * 32 + lg * 8);

    float m_run[4], l_run[4];
    f32x4 oacc[4];
#pragma unroll
    for (int r = 0; r < 4; ++r) { m_run[r] = -3e38f; l_run[r] = 0.f; }
#pragma unroll
    for (int nt = 0; nt < 4; ++nt) oacc[nt] = (f32x4){0.f, 0.f, 0.f, 0.f};

    const int xk = (lm & 7) << 4;
    const int sV = tid & 31, d0 = (tid >> 5) * 8;

    auto stageK = [&](int buf, int s0) {
#pragma unroll
        for (int j = 0; j < 8; ++j) {
            const int row = wave * 8 + j;
            g2lds16((const char*)(Kmem + ((size_t)b * SS + s0 + row) * 512) +
                        ((lane * 16) ^ (j << 4)),
                    (char*)Ks[buf] + row * 1024);
        }
    };
    auto vload = [&](int s0) -> bf16x8 {
        return *(const bf16x8*)(CV + ((size_t)b * SS + s0 + sV) * 512 + h * 64 + d0);
    };

    stageK(0, 0);
    bf16x8 vrA = vload(0), vrB;
    for (int c = 0; c < 16; ++c) {
        const int cur = c & 1;
        if (c + 1 < 16) {
            stageK(cur ^ 1, (c + 1) * 32);
            vrB = vload((c + 1) * 32);
            waitvm<9>();
        } else {
            waitvm<0>();
        }
        // commit V chunk c to LDS (transposed)
#pragma unroll
        for (int j = 0; j < 8; ++j) Vt[cur][d0 + j][sV] = (u16)vrA[j];
        asm volatile("s_waitcnt lgkmcnt(0)" ::: "memory");
        barrier_raw();
        // ---- QK^T ----
        f32x4 sc0 = (f32x4){0.f, 0.f, 0.f, 0.f};
        f32x4 sc1 = (f32x4){0.f, 0.f, 0.f, 0.f};
#pragma unroll
        for (int f = 0; f < 16; ++f) {
            const int cb = f * 64 + lg * 16;
            bf16x8 k0 = *(const bf16x8*)((const char*)Ks[cur] + lm * 1024 + (cb ^ xk));
            bf16x8 k1 = *(const bf16x8*)((const char*)Ks[cur] + (16 + lm) * 1024 + (cb ^ xk));
            sc0 = __builtin_amdgcn_mfma_f32_16x16x32_bf16(qf[f], k0, sc0, 0, 0, 0);
            sc1 = __builtin_amdgcn_mfma_f32_16x16x32_bf16(qf[f], k1, sc1, 0, 0, 0);
        }
        float sv0[4], sv1[4], tm[4];
#pragma unroll
        for (int r = 0; r < 4; ++r) {
            sv0[r] = sc0[r]; sv1[r] = sc1[r];
            tm[r] = fmaxf(sv0[r], sv1[r]);
        }
#pragma unroll
        for (int off = 1; off < 16; off <<= 1)
#pragma unroll
            for (int r = 0; r < 4; ++r) tm[r] = fmaxf(tm[r], __shfl_xor(tm[r], off));
        float fac[4], rs[4];
#pragma unroll
        for (int r = 0; r < 4; ++r) {
            const float mn = fmaxf(m_run[r], tm[r]);
            fac[r] = __expf(m_run[r] - mn);
            m_run[r] = mn;
            const float p0 = __expf(sv0[r] - mn);
            const float p1 = __expf(sv1[r] - mn);
            P[wave][lg * 4 + r][lm] = f2b(p0);
            P[wave][lg * 4 + r][16 + lm] = f2b(p1);
            rs[r] = p0 + p1;
        }
#pragma unroll
        for (int off = 1; off < 16; off <<= 1)
#pragma unroll
            for (int r = 0; r < 4; ++r) rs[r] += __shfl_xor(rs[r], off);
#pragma unroll
        for (int r = 0; r < 4; ++r) l_run[r] = l_run[r] * fac[r] + rs[r];
#pragma unroll
        for (int nt = 0; nt < 4; ++nt)
#pragma unroll
            for (int r = 0; r < 4; ++r) oacc[nt][r] *= fac[r];
        const bf16x8 pf = *(const bf16x8*)&P[wave][lm][lg * 8];
#pragma unroll
        for (int nt = 0; nt < 4; ++nt) {
            const bf16x8 vf = *(const bf16x8*)&Vt[cur][nt * 16 + lm][lg * 8];
            oacc[nt] = __builtin_amdgcn_mfma_f32_16x16x32_bf16(pf, vf, oacc[nt], 0, 0, 0);
        }
        barrier_raw();
        vrA = vrB;
    }
#pragma unroll
    for (int nt = 0; nt < 4; ++nt)
#pragma unroll
        for (int r = 0; r < 4; ++r)
            out[(size_t)(b * TT + tw + lg * 4 + r) * DD + h * 64 + nt * 16 + lm] =
                f2b(oacc[nt][r] / l_run[r]);
}

// ================= fused residual + LayerNorm =================
template <bool R1B>
__global__ __launch_bounds__(256) void add_ln(
    const void* __restrict__ R1v, const u16* __restrict__ R2,
    const float* __restrict__ g, const float* __restrict__ bta,
    float* __restrict__ outf, u16* __restrict__ outb) {
    const int row = blockIdx.x, tid = threadIdx.x;
    float x0, x1;
    if constexpr (R1B) {
        ushort2 a = ((const ushort2*)((const u16*)R1v + (size_t)row * DD))[tid];
        x0 = b2f(a.x); x1 = b2f(a.y);
    } else {
        float2 a = ((const float2*)((const float*)R1v + (size_t)row * DD))[tid];
        x0 = a.x; x1 = a.y;
    }
    ushort2 c = ((const ushort2*)(R2 + (size_t)row * DD))[tid];
    x0 += b2f(c.x); x1 += b2f(c.y);

    __shared__ float2 red[256];
    red[tid] = make_float2(x0 + x1, x0 * x0 + x1 * x1);
    __syncthreads();
#pragma unroll
    for (int o = 128; o > 0; o >>= 1) {
        if (tid < o) {
            red[tid].x += red[tid + o].x;
            red[tid].y += red[tid + o].y;
        }
        __syncthreads();
    }
    const float mean = red[0].x * (1.f / 512.f);
    const float var = red[0].y * (1.f / 512.f) - mean * mean;
    const float rstd = rsqrtf(var + 1e-5f);
    const int i = tid * 2;
    const float y0 = (x0 - mean) * rstd * g[i] + bta[i];
    const float y1 = (x1 - mean) * rstd * g[i + 1] + bta[i + 1];
    if (outf) ((float2*)(outf + (size_t)row * DD))[tid] = make_float2(y0, y1);
    if (outb) {
        ushort2 ub; ub.x = f2b(y0); ub.y = f2b(y1);
        ((ushort2*)(outb + (size_t)row * DD))[tid] = ub;
    }
}

extern "C" void kernel_launch(void* const* d_in, const int* in_sizes, int n_in,
                              void* d_out, int out_size, void* d_ws, size_t ws_size,
                              hipStream_t stream) {
    const float* tgt      = (const float*)d_in[0];
    const float* memory   = (const float*)d_in[1];
    const float* gate     = (const float*)d_in[3];
    const float* sa_in_w  = (const float*)d_in[4];
    const float* sa_in_b  = (const float*)d_in[5];
    const float* sa_out_w = (const float*)d_in[6];
    const float* sa_out_b = (const float*)d_in[7];
    const float* ca_in_w  = (const float*)d_in[8];
    const float* ca_in_b  = (const float*)d_in[9];
    const float* ca_out_w = (const float*)d_in[10];
    const float* ca_out_b = (const float*)d_in[11];
    const float* ff1_w    = (const float*)d_in[12];
    const float* ff1_b    = (const float*)d_in[13];
    const float* ff2_w    = (const float*)d_in[14];
    const float* ff2_b    = (const float*)d_in[15];
    const float* ln1_g    = (const float*)d_in[16];
    const float* ln1_b    = (const float*)d_in[17];
    const float* ln2_g    = (const float*)d_in[18];
    const float* ln2_b    = (const float*)d_in[19];
    const float* ln3_g    = (const float*)d_in[20];
    const float* ln3_b    = (const float*)d_in[21];

    // ---- workspace layout (u16 units); high-water 58,720,256 u16 = 117 MB ----
    u16* ws16     = (u16*)d_ws;
    u16* QKVb     = ws16;                    // 6291456
    u16* sa_preb  = ws16 + 6291456;          // 2097152
    u16* PRJb     = ws16 + 8388608;          // 2097152
    u16* X1b      = ws16 + 10485760;         // 2097152
    u16* memb     = ws16 + 12582912;         // 2097152  (= X1b + az)
    u16* CQb      = ws16 + 14680064;         // 2097152
    u16* CVb      = ws16 + 16777216;         // 2097152  (= CQb + cz)
    u16* QW       = ws16 + 18874368;         // 16777216 (4096 x 4096)
    u16* ca_preb  = ws16 + 35651584;         // 2097152
    u16* PRJ2b    = ws16 + 37748736;         // 2097152
    u16* X2b      = ws16 + 39845888;         // 2097152
    u16* HHb      = ws16 + 41943040;         // 8388608
    u16* F1b      = ws16 + 50331648;         // 2097152
    u16* Wreg     = ws16 + 52428800;
    u16* sa_in_wb = Wreg;                    // 786432
    u16* sa_out_wb= Wreg + 786432;           // 262144
    u16* ca_wq_b  = Wreg + 1048576;          // 262144
    u16* ca_wv_b  = Wreg + 1310720;          // 262144  (= ca_wq_b + bz)
    u16* WkT      = Wreg + 1572864;          // 262144
    u16* ca_out_wb= Wreg + 1835008;          // 262144
    u16* ff1_wb   = Wreg + 2097152;          // 1048576
    u16* ff2_wb   = Wreg + 3145728;          // 1048576
    u16* tgtb     = ws16 + 56623104;         // 2097152
    float* outf   = (float*)d_out;

    const dim3 blk(256);

    // 0. casts
    CastSegs sg;
    sg.s[0]=tgt; sg.s[1]=memory; sg.s[2]=sa_in_w; sg.s[3]=sa_out_w;
    sg.s[4]=ca_in_w; sg.s[5]=ca_in_w + (size_t)1024*512; sg.s[6]=ca_out_w;
    sg.s[7]=ff1_w; sg.s[8]=ff2_w;
    sg.d[0]=tgtb; sg.d[1]=memb; sg.d[2]=sa_in_wb; sg.d[3]=sa_out_wb;
    sg.d[4]=ca_wq_b; sg.d[5]=ca_wv_b; sg.d[6]=ca_out_wb;
    sg.d[7]=ff1_wb; sg.d[8]=ff2_wb;
    {
        const int n4[9] = {524288,524288,196608,65536,65536,65536,65536,262144,262144};
        int c = 0;
        for (int i = 0; i < 9; ++i) { sg.cum[i] = c; c += n4[i]; }
        sg.cum[9] = c;
    }
    cast_multi<<<2048, blk, 0, stream>>>(sg);
    wkt_kernel<<<1024, blk, 0, stream>>>(ca_in_w, WkT);

    // 1. QKV (4096,1536)
    gemm_bf16<128,false,false><<<dim3(12,32,1), blk, 0, stream>>>(
        tgtb,512,0, sa_in_wb,512,0, sa_in_b,sa_in_b,nullptr,
        QKVb,1536,0, 512, 1.f,1.f);
    // 2. self flash -> sa_preb
    flash_self<<<dim3(8,8,8), blk, 0, stream>>>(QKVb, sa_preb);
    // 3. proj1
    gemm_bf16<64,false,false><<<dim3(8,32,1), blk, 0, stream>>>(
        sa_preb,512,0, sa_out_wb,512,0, sa_out_b,sa_out_b,nullptr,
        PRJb,512,0, 512, 1.f,1.f);
    // 4. LN1 -> X1b
    add_ln<false><<<4096, blk, 0, stream>>>(tgt, PRJb, ln1_g, ln1_b, nullptr, X1b);
    // 5. cq (z=0, alpha .125) + cv (z=1) batched
    gemm_bf16<64,false,false><<<dim3(8,32,2), blk, 0, stream>>>(
        X1b,512,2097152, ca_wq_b,512,262144, ca_in_b, ca_in_b+1024, nullptr,
        CQb,512,2097152, 512, 0.125f, 1.f);
    // 6. qWg all heads (z=8, K=64) -> QW (4096,4096)
    gemm_bf16<64,false,true><<<dim3(8,32,8), blk, 0, stream>>>(
        CQb,512,64, WkT,64,32768, nullptr,nullptr,gate,
        QW,4096,512, 64, 1.f,1.f);
    // 7. cross flash (all heads) -> ca_preb
    flash_cross<<<dim3(8,8,8), blk, 0, stream>>>(QW, memb, CVb, ca_preb);
    // 8. proj2
    gemm_bf16<64,false,false><<<dim3(8,32,1), blk, 0, stream>>>(
        ca_preb,512,0, ca_out_wb,512,0, ca_out_b,ca_out_b,nullptr,
        PRJ2b,512,0, 512, 1.f,1.f);
    // 9. LN2 -> X2b
    add_ln<true><<<4096, blk, 0, stream>>>(X1b, PRJ2b, ln2_g, ln2_b, nullptr, X2b);
    // 10. ff1 + relu -> HHb
    gemm_bf16<128,true,false><<<dim3(16,32,1), blk, 0, stream>>>(
        X2b,512,0, ff1_wb,512,0, ff1_b,ff1_b,nullptr,
        HHb,2048,0, 512, 1.f,1.f);
    // 11. ff2 -> F1b
    gemm_bf16<64,false,false><<<dim3(8,32,1), blk, 0, stream>>>(
        HHb,2048,0, ff2_wb,2048,0, ff2_b,ff2_b,nullptr,
        F1b,512,0, 2048, 1.f,1.f);
    // 12. LN3 -> d_out
    add_ln<true><<<4096, blk, 0, stream>>>(X2b, F1b, ln3_g, ln3_b, outf, nullptr);

    (void)in_sizes; (void)n_in; (void)out_size; (void)ws_size;
}